// Round 1
// baseline (2235.106 us; speedup 1.0000x reference)
//
#include <hip/hip_runtime.h>

#define H 128
#define NNODES 10000
#define NEDGES 320000
#define NBATCH 2

__device__ __forceinline__ float silu_f(float v) {
    return v / (1.0f + __expf(-v));
}

// -------------------------------------------------------------------------
// Kernel 1: per-node in-degree counts (f32 so the divide matches reference)
// -------------------------------------------------------------------------
__global__ __launch_bounds__(256) void cnt_kernel(const int* __restrict__ recv,
                                                  float* __restrict__ cnt) {
    int e = blockIdx.x * 256 + threadIdx.x;
    if (e < NEDGES) atomicAdd(&cnt[recv[e]], 1.0f);
}

// -------------------------------------------------------------------------
// Kernel 2: fused message MLP + scatter-add
//   per block: 32 edges (fixed batch b), feats [32][384] staged in LDS,
//   GEMM1 (K=384, N=128) -> SiLU -> GEMM2 (K=128, N=128) -> SiLU
//   -> write msg, atomicAdd into agg[b][recv][.]
//   LDS: 32*384*4 + 32*128*4 = 64 KiB exactly -> 2 blocks/CU
// -------------------------------------------------------------------------
#define MT_ROWS 32

__global__ __launch_bounds__(256) void msg_kernel(
    const float* __restrict__ x, const float* __restrict__ ea,
    const int* __restrict__ send, const int* __restrict__ recv,
    const float* __restrict__ w1, const float* __restrict__ b1,
    const float* __restrict__ w2, const float* __restrict__ b2,
    float* __restrict__ msg_out, float* __restrict__ agg)
{
    __shared__ float feats[MT_ROWS * 384];
    __shared__ float hbuf[MT_ROWS * 128];

    const int b   = blockIdx.y;
    const int e0  = blockIdx.x * MT_ROWS;
    const int tid = threadIdx.x;

    // ---- stage feats: each of 256 threads loads 12 float4 of one row ----
    {
        const int row = tid >> 3;   // 0..31
        const int l8  = tid & 7;    // 0..7
        const int e   = e0 + row;
        const int se  = send[e];
        const int re  = recv[e];
        const float* xs = x  + ((size_t)b * NNODES + se) * H;
        const float* xr = x  + ((size_t)b * NNODES + re) * H;
        const float* er = ea + ((size_t)b * NEDGES + e)  * H;
        #pragma unroll
        for (int i = 0; i < 12; ++i) {
            const int seg = l8 + i * 8;                    // 0..95
            const float* src = (seg < 32) ? (xs + seg * 4)
                             : (seg < 64) ? (xr + (seg - 32) * 4)
                                          : (er + (seg - 64) * 4);
            *(float4*)&feats[row * 384 + seg * 4] = *(const float4*)src;
        }
    }
    __syncthreads();

    const int tx = tid & 31;   // 32 col groups of 4 -> 128 cols
    const int ty = tid >> 5;   // 8 row groups of 4  -> 32 rows

    // ---- GEMM1: [32 x 384] @ [384 x 128] ----
    float acc[4][4] = {{0.f}};
    for (int k = 0; k < 384; k += 4) {
        float4 f[4];
        #pragma unroll
        for (int i = 0; i < 4; ++i)
            f[i] = *(const float4*)&feats[(ty * 4 + i) * 384 + k];
        #pragma unroll
        for (int kk = 0; kk < 4; ++kk) {
            const float4 wv = *(const float4*)&w1[(size_t)(k + kk) * H + tx * 4];
            #pragma unroll
            for (int i = 0; i < 4; ++i) {
                const float fv = ((const float*)&f[i])[kk];
                acc[i][0] += fv * wv.x;
                acc[i][1] += fv * wv.y;
                acc[i][2] += fv * wv.z;
                acc[i][3] += fv * wv.w;
            }
        }
    }
    {
        const float4 bv = *(const float4*)&b1[tx * 4];
        #pragma unroll
        for (int i = 0; i < 4; ++i) {
            float4 v;
            v.x = silu_f(acc[i][0] + bv.x);
            v.y = silu_f(acc[i][1] + bv.y);
            v.z = silu_f(acc[i][2] + bv.z);
            v.w = silu_f(acc[i][3] + bv.w);
            *(float4*)&hbuf[(ty * 4 + i) * 128 + tx * 4] = v;
        }
    }
    __syncthreads();

    // ---- GEMM2: [32 x 128] @ [128 x 128] ----
    float acc2[4][4] = {{0.f}};
    for (int k = 0; k < 128; k += 4) {
        float4 f[4];
        #pragma unroll
        for (int i = 0; i < 4; ++i)
            f[i] = *(const float4*)&hbuf[(ty * 4 + i) * 128 + k];
        #pragma unroll
        for (int kk = 0; kk < 4; ++kk) {
            const float4 wv = *(const float4*)&w2[(size_t)(k + kk) * H + tx * 4];
            #pragma unroll
            for (int i = 0; i < 4; ++i) {
                const float fv = ((const float*)&f[i])[kk];
                acc2[i][0] += fv * wv.x;
                acc2[i][1] += fv * wv.y;
                acc2[i][2] += fv * wv.z;
                acc2[i][3] += fv * wv.w;
            }
        }
    }

    // ---- epilogue: SiLU, write msg, scatter into agg ----
    {
        const int c = tx * 4;
        const float4 bv = *(const float4*)&b2[c];
        #pragma unroll
        for (int i = 0; i < 4; ++i) {
            const int e = e0 + ty * 4 + i;
            float4 v;
            v.x = silu_f(acc2[i][0] + bv.x);
            v.y = silu_f(acc2[i][1] + bv.y);
            v.z = silu_f(acc2[i][2] + bv.z);
            v.w = silu_f(acc2[i][3] + bv.w);
            *(float4*)&msg_out[((size_t)b * NEDGES + e) * H + c] = v;
            const int rn = recv[e];
            float* arow = agg + ((size_t)b * NNODES + rn) * H + c;
            atomicAdd(arow + 0, v.x);
            atomicAdd(arow + 1, v.y);
            atomicAdd(arow + 2, v.z);
            atomicAdd(arow + 3, v.w);
        }
    }
}

// -------------------------------------------------------------------------
// Kernel 3: fused normalize + residual + update MLP
//   per block: 16 node-rows; xp = x + agg/max(cnt,1) staged in LDS,
//   GEMM (K=128, N=256) -> SiLU -> GEMM (K=256, N=128) -> + residual
// -------------------------------------------------------------------------
#define XPS 132   // 128 + 4 pad (float4-aligned)
#define UBS 260   // 256 + 4 pad

__global__ __launch_bounds__(256) void upd_kernel(
    const float* __restrict__ x, const float* __restrict__ agg,
    const float* __restrict__ cnt,
    const float* __restrict__ wu1, const float* __restrict__ bu1,
    const float* __restrict__ wu2, const float* __restrict__ bu2,
    float* __restrict__ xout)
{
    __shared__ float xp[16 * XPS];
    __shared__ float ub[16 * UBS];

    const int tid = threadIdx.x;
    const int r0  = blockIdx.x * 16;

    // ---- stage xp = x + agg / max(cnt,1) ----
    {
        const int row = tid >> 4;   // 0..15
        const int l   = tid & 15;   // 0..15, 2 float4 each
        const int gr  = r0 + row;   // b*N + n
        const int n   = gr % NNODES;
        const float rc = 1.0f / fmaxf(cnt[n], 1.0f);
        #pragma unroll
        for (int i = 0; i < 2; ++i) {
            const int c4 = (l + i * 16) * 4;
            const float4 xv = *(const float4*)&x[(size_t)gr * H + c4];
            const float4 av = *(const float4*)&agg[(size_t)gr * H + c4];
            float4 o;
            o.x = xv.x + av.x * rc;
            o.y = xv.y + av.y * rc;
            o.z = xv.z + av.z * rc;
            o.w = xv.w + av.w * rc;
            *(float4*)&xp[row * XPS + c4] = o;
        }
    }
    __syncthreads();

    const int tx = tid & 15;   // col groups
    const int ty = tid >> 4;   // row 0..15
    const int gr = r0 + ty;

    // ---- GEMM u1: [16 x 128] @ [128 x 256] ----
    float acc[4][4] = {{0.f}};
    for (int k = 0; k < 128; k += 4) {
        const float4 f = *(const float4*)&xp[ty * XPS + k];
        #pragma unroll
        for (int kk = 0; kk < 4; ++kk) {
            const float fv = ((const float*)&f)[kk];
            #pragma unroll
            for (int g = 0; g < 4; ++g) {
                const float4 wv = *(const float4*)&wu1[(size_t)(k + kk) * 256 + g * 64 + tx * 4];
                acc[g][0] += fv * wv.x;
                acc[g][1] += fv * wv.y;
                acc[g][2] += fv * wv.z;
                acc[g][3] += fv * wv.w;
            }
        }
    }
    #pragma unroll
    for (int g = 0; g < 4; ++g) {
        const int c = g * 64 + tx * 4;
        const float4 bv = *(const float4*)&bu1[c];
        float4 v;
        v.x = silu_f(acc[g][0] + bv.x);
        v.y = silu_f(acc[g][1] + bv.y);
        v.z = silu_f(acc[g][2] + bv.z);
        v.w = silu_f(acc[g][3] + bv.w);
        *(float4*)&ub[ty * UBS + c] = v;
    }
    __syncthreads();

    // ---- GEMM u2: [16 x 256] @ [256 x 128] ----
    float acc2[2][4] = {{0.f}};
    for (int k = 0; k < 256; k += 4) {
        const float4 f = *(const float4*)&ub[ty * UBS + k];
        #pragma unroll
        for (int kk = 0; kk < 4; ++kk) {
            const float fv = ((const float*)&f)[kk];
            #pragma unroll
            for (int g = 0; g < 2; ++g) {
                const float4 wv = *(const float4*)&wu2[(size_t)(k + kk) * H + g * 64 + tx * 4];
                acc2[g][0] += fv * wv.x;
                acc2[g][1] += fv * wv.y;
                acc2[g][2] += fv * wv.z;
                acc2[g][3] += fv * wv.w;
            }
        }
    }
    #pragma unroll
    for (int g = 0; g < 2; ++g) {
        const int c = g * 64 + tx * 4;
        const float4 bv  = *(const float4*)&bu2[c];
        const float4 xpv = *(const float4*)&xp[ty * XPS + c];
        float4 o;
        o.x = xpv.x + acc2[g][0] + bv.x;
        o.y = xpv.y + acc2[g][1] + bv.y;
        o.z = xpv.z + acc2[g][2] + bv.z;
        o.w = xpv.w + acc2[g][3] + bv.w;
        *(float4*)&xout[(size_t)gr * H + c] = o;
    }
}

// -------------------------------------------------------------------------
extern "C" void kernel_launch(void* const* d_in, const int* in_sizes, int n_in,
                              void* d_out, int out_size, void* d_ws, size_t ws_size,
                              hipStream_t stream) {
    const float* x    = (const float*)d_in[0];
    const float* ea   = (const float*)d_in[1];
    const int*   send = (const int*)d_in[2];
    const int*   recv = (const int*)d_in[3];
    const float* w1   = (const float*)d_in[4];
    const float* b1   = (const float*)d_in[5];
    const float* w2   = (const float*)d_in[6];
    const float* b2   = (const float*)d_in[7];
    const float* wu1  = (const float*)d_in[8];
    const float* bu1  = (const float*)d_in[9];
    const float* wu2  = (const float*)d_in[10];
    const float* bu2  = (const float*)d_in[11];

    float* xout    = (float*)d_out;                                  // [B,N,H]
    float* msg_out = xout + (size_t)NBATCH * NNODES * H;             // [B,E,H]

    float* agg = (float*)d_ws;                                       // [B,N,H]
    float* cnt = agg + (size_t)NBATCH * NNODES * H;                  // [N]

    // zero agg + cnt (ws is re-poisoned to 0xAA before every launch)
    hipMemsetAsync(d_ws, 0,
                   ((size_t)NBATCH * NNODES * H + NNODES) * sizeof(float),
                   stream);

    cnt_kernel<<<NEDGES / 256, 256, 0, stream>>>(recv, cnt);

    msg_kernel<<<dim3(NEDGES / MT_ROWS, NBATCH), 256, 0, stream>>>(
        x, ea, send, recv, w1, b1, w2, b2, msg_out, agg);

    upd_kernel<<<(NBATCH * NNODES) / 16, 256, 0, stream>>>(
        x, agg, cnt, wu1, bu1, wu2, bu2, xout);
}

// Round 3
// 1255.019 us; speedup vs baseline: 1.7809x; 1.7809x over previous
//
#include <hip/hip_runtime.h>
#include <hip/hip_fp16.h>

#define H 128
#define NNODES 10000
#define NEDGES 320000
#define NBATCH 2

typedef _Float16 half4_t __attribute__((ext_vector_type(4)));
typedef _Float16 half8_t __attribute__((ext_vector_type(8)));
typedef float f32x4_t __attribute__((ext_vector_type(4)));

__device__ __forceinline__ float silu_f(float v) {
    return v / (1.0f + __expf(-v));
}

// -------------------------------------------------------------------------
// Weight prep: w1t[n][k] = (f16) w1[k][n]  (128 x 384), w2t (128 x 128)
// -------------------------------------------------------------------------
__global__ __launch_bounds__(256) void convw_kernel(
    const float* __restrict__ w1, const float* __restrict__ w2,
    _Float16* __restrict__ w1t, _Float16* __restrict__ w2t)
{
    const int i = blockIdx.x * 256 + threadIdx.x;
    if (i < 128 * 384) {
        const int n = i / 384, k = i - n * 384;
        w1t[i] = (_Float16)w1[k * 128 + n];
    } else {
        const int j = i - 128 * 384;
        if (j < 128 * 128) {
            const int n = j / 128, k = j - n * 128;
            w2t[j] = (_Float16)w2[k * 128 + n];
        }
    }
}

// -------------------------------------------------------------------------
// Kernel 1: per-node in-degree counts
// -------------------------------------------------------------------------
__global__ __launch_bounds__(256) void cnt_kernel(const int* __restrict__ recv,
                                                  float* __restrict__ cnt) {
    int e = blockIdx.x * 256 + threadIdx.x;
    if (e < NEDGES) atomicAdd(&cnt[recv[e]], 1.0f);
}

// -------------------------------------------------------------------------
// Kernel 2: fused message MLP (f16 MFMA) + packed-f16 scatter-add
//   block = 256 thr = 4 waves; 64 edges/block; waves split N (32 each).
//   Swapped operands: compute msg^T = Wt . feats^T with
//   mfma_f32_16x16x32_f16: A = weight frag (reg-resident), B = feats frag.
//   A-frag: lane: row n = l&15, k = (l>>4)*8+j  -> contiguous from w1t[n][k]
//   B-frag: lane: col m = l&15, k = (l>>4)*8+j  -> contiguous from feats[m][k]
//   D-frag: lane: n = (l>>4)*4 + r, m = l&15
// -------------------------------------------------------------------------
#define FSTRIDE 392   // 384 + 8 f16 pad -> 784B row stride, conflict-free b128

__global__ __launch_bounds__(256, 2) void msg_mfma_kernel(
    const float* __restrict__ x, const float* __restrict__ ea,
    const int* __restrict__ send, const int* __restrict__ recv,
    const _Float16* __restrict__ w1t, const float* __restrict__ b1,
    const _Float16* __restrict__ w2t, const float* __restrict__ b2,
    float* __restrict__ msg_out, _Float16* __restrict__ aggh)
{
    __shared__ _Float16 smem[64 * FSTRIDE];   // 50176 B
    _Float16* hbuf = smem;                    // aliased: [32 nblk][64 m][4] f16

    const int tid  = threadIdx.x;
    const int lane = tid & 63;
    const int wave = tid >> 6;
    const int q    = lane >> 4;    // 0..3
    const int r16  = lane & 15;
    const int b    = blockIdx.y;
    const int e0   = blockIdx.x * 64;

    // ---- GEMM1 weight frags -> registers (96 VGPR), L2-served ----
    half8_t w1f[12][2];
    #pragma unroll
    for (int kt = 0; kt < 12; ++kt)
        #pragma unroll
        for (int nt = 0; nt < 2; ++nt) {
            const int n = wave * 32 + nt * 16 + r16;
            w1f[kt][nt] = *(const half8_t*)&w1t[n * 384 + kt * 32 + q * 8];
        }

    // ---- stage feats tile [64][384] as f16 (gather + convert) ----
    {
        const int row = tid >> 2;       // 0..63
        const int l4  = tid & 3;
        const int e   = e0 + row;
        const float* xs = x  + ((size_t)b * NNODES + send[e]) * H;
        const float* xr = x  + ((size_t)b * NNODES + recv[e]) * H;
        const float* er = ea + ((size_t)b * NEDGES + e) * H;
        #pragma unroll
        for (int i = 0; i < 24; ++i) {
            const int seg = l4 + i * 4;   // 0..95
            const int c   = seg * 4;
            const float4 v = (c < 128) ? *(const float4*)&xs[c]
                           : (c < 256) ? *(const float4*)&xr[c - 128]
                                       : *(const float4*)&er[c - 256];
            half4_t h;
            h[0] = (_Float16)v.x; h[1] = (_Float16)v.y;
            h[2] = (_Float16)v.z; h[3] = (_Float16)v.w;
            *(half4_t*)&smem[row * FSTRIDE + c] = h;
        }
    }
    __syncthreads();

    // ---- GEMM1: msg^T pre-act = w1^T . feats^T  (K=384) ----
    f32x4_t acc1[4][2];
    #pragma unroll
    for (int mt = 0; mt < 4; ++mt)
        #pragma unroll
        for (int nt = 0; nt < 2; ++nt)
            acc1[mt][nt] = (f32x4_t){0.f, 0.f, 0.f, 0.f};

    #pragma unroll
    for (int kt = 0; kt < 12; ++kt) {
        #pragma unroll
        for (int mt = 0; mt < 4; ++mt) {
            const half8_t fB =
                *(const half8_t*)&smem[(mt * 16 + r16) * FSTRIDE + kt * 32 + q * 8];
            #pragma unroll
            for (int nt = 0; nt < 2; ++nt)
                acc1[mt][nt] = __builtin_amdgcn_mfma_f32_16x16x32_f16(
                    w1f[kt][nt], fB, acc1[mt][nt], 0, 0, 0);
        }
    }
    __syncthreads();   // all GEMM1 LDS reads done before hbuf (alias) writes

    // ---- h = silu(. + b1) -> hbuf [nblk][m][4] f16 ----
    #pragma unroll
    for (int nt = 0; nt < 2; ++nt) {
        const float4 bv = *(const float4*)&b1[wave * 32 + nt * 16 + q * 4];
        const int blk = wave * 8 + nt * 4 + q;   // n/4
        #pragma unroll
        for (int mt = 0; mt < 4; ++mt) {
            half4_t hv;
            hv[0] = (_Float16)silu_f(acc1[mt][nt][0] + bv.x);
            hv[1] = (_Float16)silu_f(acc1[mt][nt][1] + bv.y);
            hv[2] = (_Float16)silu_f(acc1[mt][nt][2] + bv.z);
            hv[3] = (_Float16)silu_f(acc1[mt][nt][3] + bv.w);
            *(half4_t*)&hbuf[(blk * 64 + mt * 16 + r16) * 4] = hv;
        }
    }

    // GEMM2 weight frags while waiting on the barrier
    half8_t w2f[4][2];
    #pragma unroll
    for (int kt = 0; kt < 4; ++kt)
        #pragma unroll
        for (int nt = 0; nt < 2; ++nt) {
            const int n = wave * 32 + nt * 16 + r16;
            w2f[kt][nt] = *(const half8_t*)&w2t[n * 128 + kt * 32 + q * 8];
        }
    __syncthreads();

    // ---- GEMM2: msg^T = w2^T . h^T  (K=128) ----
    f32x4_t acc2[4][2];
    #pragma unroll
    for (int mt = 0; mt < 4; ++mt)
        #pragma unroll
        for (int nt = 0; nt < 2; ++nt)
            acc2[mt][nt] = (f32x4_t){0.f, 0.f, 0.f, 0.f};

    #pragma unroll
    for (int kt = 0; kt < 4; ++kt) {
        #pragma unroll
        for (int mt = 0; mt < 4; ++mt) {
            const int blk0 = kt * 8 + q * 2;
            const half4_t lo = *(const half4_t*)&hbuf[((blk0    ) * 64 + mt * 16 + r16) * 4];
            const half4_t hi = *(const half4_t*)&hbuf[((blk0 + 1) * 64 + mt * 16 + r16) * 4];
            const half8_t fB = __builtin_shufflevector(lo, hi, 0, 1, 2, 3, 4, 5, 6, 7);
            #pragma unroll
            for (int nt = 0; nt < 2; ++nt)
                acc2[mt][nt] = __builtin_amdgcn_mfma_f32_16x16x32_f16(
                    w2f[kt][nt], fB, acc2[mt][nt], 0, 0, 0);
        }
    }

    // ---- epilogue: silu + b2, write msg (f32), pk-f16 atomic scatter ----
    #pragma unroll
    for (int mt = 0; mt < 4; ++mt) {
        const int e  = e0 + mt * 16 + r16;
        const int rn = recv[e];
        float*     mrow = msg_out + ((size_t)b * NEDGES + e) * H;
        _Float16*  arow = aggh    + ((size_t)b * NNODES + rn) * H;
        #pragma unroll
        for (int nt = 0; nt < 2; ++nt) {
            const int n = wave * 32 + nt * 16 + q * 4;
            const float4 bv = *(const float4*)&b2[n];
            float4 v;
            v.x = silu_f(acc2[mt][nt][0] + bv.x);
            v.y = silu_f(acc2[mt][nt][1] + bv.y);
            v.z = silu_f(acc2[mt][nt][2] + bv.z);
            v.w = silu_f(acc2[mt][nt][3] + bv.w);
            *(float4*)&mrow[n] = v;
            unsafeAtomicAdd((__half2*)&arow[n],     __floats2half2_rn(v.x, v.y));
            unsafeAtomicAdd((__half2*)&arow[n + 2], __floats2half2_rn(v.z, v.w));
        }
    }
}

// -------------------------------------------------------------------------
// Kernel 3: fused normalize + residual + update MLP (f32 VALU)
// -------------------------------------------------------------------------
#define XPS 132   // 128 + 4 pad
#define UBS 260   // 256 + 4 pad

__global__ __launch_bounds__(256) void upd_kernel(
    const float* __restrict__ x, const _Float16* __restrict__ aggh,
    const float* __restrict__ cnt,
    const float* __restrict__ wu1, const float* __restrict__ bu1,
    const float* __restrict__ wu2, const float* __restrict__ bu2,
    float* __restrict__ xout)
{
    __shared__ float xp[16 * XPS];
    __shared__ float ub[16 * UBS];

    const int tid = threadIdx.x;
    const int r0  = blockIdx.x * 16;

    // ---- stage xp = x + agg / max(cnt,1) ----
    {
        const int row = tid >> 4;   // 0..15
        const int l   = tid & 15;
        const int gr  = r0 + row;   // b*N + n
        const int n   = gr % NNODES;
        const float rc = 1.0f / fmaxf(cnt[n], 1.0f);
        #pragma unroll
        for (int i = 0; i < 2; ++i) {
            const int c4 = (l + i * 16) * 4;
            const float4  xv = *(const float4*)&x[(size_t)gr * H + c4];
            const half4_t av = *(const half4_t*)&aggh[(size_t)gr * H + c4];
            float4 o;
            o.x = xv.x + (float)av[0] * rc;
            o.y = xv.y + (float)av[1] * rc;
            o.z = xv.z + (float)av[2] * rc;
            o.w = xv.w + (float)av[3] * rc;
            *(float4*)&xp[row * XPS + c4] = o;
        }
    }
    __syncthreads();

    const int tx = tid & 15;
    const int ty = tid >> 4;
    const int gr = r0 + ty;

    // ---- GEMM u1: [16 x 128] @ [128 x 256] ----
    float acc[4][4] = {{0.f}};
    for (int k = 0; k < 128; k += 4) {
        const float4 f = *(const float4*)&xp[ty * XPS + k];
        #pragma unroll
        for (int kk = 0; kk < 4; ++kk) {
            const float fv = ((const float*)&f)[kk];
            #pragma unroll
            for (int g = 0; g < 4; ++g) {
                const float4 wv = *(const float4*)&wu1[(size_t)(k + kk) * 256 + g * 64 + tx * 4];
                acc[g][0] += fv * wv.x;
                acc[g][1] += fv * wv.y;
                acc[g][2] += fv * wv.z;
                acc[g][3] += fv * wv.w;
            }
        }
    }
    #pragma unroll
    for (int g = 0; g < 4; ++g) {
        const int c = g * 64 + tx * 4;
        const float4 bv = *(const float4*)&bu1[c];
        float4 v;
        v.x = silu_f(acc[g][0] + bv.x);
        v.y = silu_f(acc[g][1] + bv.y);
        v.z = silu_f(acc[g][2] + bv.z);
        v.w = silu_f(acc[g][3] + bv.w);
        *(float4*)&ub[ty * UBS + c] = v;
    }
    __syncthreads();

    // ---- GEMM u2: [16 x 256] @ [256 x 128] ----
    float acc2[2][4] = {{0.f}};
    for (int k = 0; k < 256; k += 4) {
        const float4 f = *(const float4*)&ub[ty * UBS + k];
        #pragma unroll
        for (int kk = 0; kk < 4; ++kk) {
            const float fv = ((const float*)&f)[kk];
            #pragma unroll
            for (int g = 0; g < 2; ++g) {
                const float4 wv = *(const float4*)&wu2[(size_t)(k + kk) * H + g * 64 + tx * 4];
                acc2[g][0] += fv * wv.x;
                acc2[g][1] += fv * wv.y;
                acc2[g][2] += fv * wv.z;
                acc2[g][3] += fv * wv.w;
            }
        }
    }
    #pragma unroll
    for (int g = 0; g < 2; ++g) {
        const int c = g * 64 + tx * 4;
        const float4 bv  = *(const float4*)&bu2[c];
        const float4 xpv = *(const float4*)&xp[ty * XPS + c];
        float4 o;
        o.x = xpv.x + acc2[g][0] + bv.x;
        o.y = xpv.y + acc2[g][1] + bv.y;
        o.z = xpv.z + acc2[g][2] + bv.z;
        o.w = xpv.w + acc2[g][3] + bv.w;
        *(float4*)&xout[(size_t)gr * H + c] = o;
    }
}

// -------------------------------------------------------------------------
extern "C" void kernel_launch(void* const* d_in, const int* in_sizes, int n_in,
                              void* d_out, int out_size, void* d_ws, size_t ws_size,
                              hipStream_t stream) {
    const float* x    = (const float*)d_in[0];
    const float* ea   = (const float*)d_in[1];
    const int*   send = (const int*)d_in[2];
    const int*   recv = (const int*)d_in[3];
    const float* w1   = (const float*)d_in[4];
    const float* b1   = (const float*)d_in[5];
    const float* w2   = (const float*)d_in[6];
    const float* b2   = (const float*)d_in[7];
    const float* wu1  = (const float*)d_in[8];
    const float* bu1  = (const float*)d_in[9];
    const float* wu2  = (const float*)d_in[10];
    const float* bu2  = (const float*)d_in[11];

    float* xout    = (float*)d_out;                                  // [B,N,H]
    float* msg_out = xout + (size_t)NBATCH * NNODES * H;             // [B,E,H]

    // ws layout: aggh (f16) | cnt (f32) | w1t (f16) | w2t (f16)
    char* ws = (char*)d_ws;
    _Float16* aggh = (_Float16*)ws;                          // 2*10000*128*2 = 5,120,000 B
    float*    cnt  = (float*)(ws + 5120000);                 // 40,000 B
    _Float16* w1t  = (_Float16*)(ws + 5160000);              // 98,304 B
    _Float16* w2t  = (_Float16*)(ws + 5258304);              // 32,768 B

    // zero aggh + cnt (f16 zero == 0x0000)
    hipMemsetAsync(d_ws, 0, 5160000, stream);

    convw_kernel<<<(128 * 384 + 128 * 128) / 256, 256, 0, stream>>>(w1, w2, w1t, w2t);

    cnt_kernel<<<NEDGES / 256, 256, 0, stream>>>(recv, cnt);

    msg_mfma_kernel<<<dim3(NEDGES / 64, NBATCH), 256, 0, stream>>>(
        x, ea, send, recv, w1t, b1, w2t, b2, msg_out, aggh);

    upd_kernel<<<(NBATCH * NNODES) / 16, 256, 0, stream>>>(
        x, aggh, cnt, wu1, bu1, wu2, bu2, xout);
}